// Round 12
// baseline (803.345 us; speedup 1.0000x reference)
//
#include <hip/hip_runtime.h>
#include <hip/hip_bf16.h>
#include <hip/hip_fp16.h>

// GAT layer on MI355X (gfx950).
//   x: (N=50000, K=256) fp32, W: (K=256, F=64) fp32, a: (1, 128) fp32
//   edge_index: (2, E=1600000) int (src row 0, dst row 1)
// out = elu( segsum_src(e * h[dst]) / segsum_src(e) ),
//   e = exp(-leakyrelu(s_src[src]+s_dst[dst], 0.2)), h = x@W
//
// Round 22: sortgather's 50us proved invariant to every parameter (grid,
// LDS, streams, prefetch, occupancy) -> the STRUCTURE (2 scans + sort +
// barrier-aligned reduce) is the cost. Replaced with sortless single-pass
// scatter-accumulate: one 512-thr block per bucket, acc[64][65] fp32 in
// LDS (stride-65 = conflict-free), per-edge fire-and-forget ds_add_f32,
// no barriers during accumulation, then divide+elu+store. K_A reverted to
// the R18/R20 verified version (single changed variable).

#define ALPHA 0.2f
#define KDIM 256
#define FDIM 64
#define WPAD 8             // bf16 row pad: row stride 264 elems = 528B
#define ACC_STRIDE 65      // fp32 acc row stride: banks (sl+8*oct+j)%32, 2-way max
#define BIN_CHUNK 8192
#define BUCKET_CAP 4096    // 64-src bucket: mean ~2046 edges; >40 sigma slack

typedef __bf16 bf16x8 __attribute__((ext_vector_type(8)));
typedef float f32x4 __attribute__((ext_vector_type(4)));
typedef unsigned int u32;
typedef unsigned short u16;

union SmemA {
    struct { int hist[1024]; int lcur[1024]; } bin;   // 8 KB
    __bf16 w[FDIM * (KDIM + WPAD)];                   // 33 KB  w[n][k]
};

// ---------------------------------------------------------------------------
// Kernel A (fused): blocks [0,NBLK) = bin; blocks [NBLK, NBLK+GB) = gemm.
// (byte-identical to round-18/20 verified version)
// ---------------------------------------------------------------------------
__global__ __launch_bounds__(256) void gat_gemm_bin_kernel(
    const float* __restrict__ x, const float* __restrict__ W,
    const float* __restrict__ a, __hip_bfloat16* __restrict__ h_bf,
    float* __restrict__ s_src, float* __restrict__ s_dst,
    const int* __restrict__ srcA, const int* __restrict__ dstA,
    int* __restrict__ bcur, u32* __restrict__ pair,
    int N, int E, int NBU, int NBLK)
{
    __shared__ SmemA sm;
    const int t = threadIdx.x;

    if ((int)blockIdx.x < NBLK) {
        // ---------------- bin path ----------------
        for (int j = t; j < 1024; j += 256) sm.bin.hist[j] = 0;
        __syncthreads();
        const int base = blockIdx.x * BIN_CHUNK;
        const int cnt = min(BIN_CHUNK, E - base);
        for (int i = t; i < cnt; i += 256)
            atomicAdd(&sm.bin.hist[srcA[base + i] >> 6], 1);
        __syncthreads();
        for (int j = t; j < NBU; j += 256) {
            const int v = sm.bin.hist[j];
            sm.bin.lcur[j] = v ? (j * BUCKET_CAP + atomicAdd(&bcur[j], v)) : 0;
        }
        __syncthreads();
        for (int i = t; i < cnt; i += 256) {
            const int s = srcA[base + i];
            const int d = dstA[base + i];
            const int pos = atomicAdd(&sm.bin.lcur[s >> 6], 1);
            pair[pos] = ((u32)(s & 63) << 16) | (u32)d;   // d < 65536
        }
        return;
    }

    // ---------------- gemm path ----------------
    for (int i = t; i < KDIM * FDIM; i += 256) {
        const int k = i >> 6;
        const int n = i & 63;
        sm.w[n * (KDIM + WPAD) + k] = (__bf16)W[i];
    }
    __syncthreads();

    const int gb = (int)blockIdx.x - NBLK;
    const int lane = t & 63;
    const int wv = t >> 6;              // 0..3
    const int m0 = gb * 64 + wv * 16;   // this wave: rows m0..m0+15
    const int c = lane & 15;
    const int q = lane >> 4;

    const int r0 = m0 + c;
    const float* xp0 = x + (long)(r0 < N ? r0 : N - 1) * KDIM;

    f32x4 acc[4];
#pragma unroll
    for (int ct = 0; ct < 4; ++ct) acc[ct] = (f32x4){0.f, 0.f, 0.f, 0.f};

#pragma unroll 4
    for (int kc = 0; kc < 8; ++kc) {
        const int k0 = kc * 32 + q * 8;
        const float4 xa0 = *(const float4*)(xp0 + k0);
        const float4 xb0 = *(const float4*)(xp0 + k0 + 4);
        bf16x8 af0;
        af0[0] = (__bf16)xa0.x; af0[1] = (__bf16)xa0.y;
        af0[2] = (__bf16)xa0.z; af0[3] = (__bf16)xa0.w;
        af0[4] = (__bf16)xb0.x; af0[5] = (__bf16)xb0.y;
        af0[6] = (__bf16)xb0.z; af0[7] = (__bf16)xb0.w;
#pragma unroll
        for (int ct = 0; ct < 4; ++ct) {
            const bf16x8 bf = *(const bf16x8*)(&sm.w[(ct * 16 + c) * (KDIM + WPAD) + k0]);
            acc[ct] = __builtin_amdgcn_mfma_f32_16x16x32_bf16(af0, bf, acc[ct], 0, 0, 0);
        }
    }

    float a1c[4], a2c[4];
#pragma unroll
    for (int ct = 0; ct < 4; ++ct) {
        a1c[ct] = a[ct * 16 + c];
        a2c[ct] = a[FDIM + ct * 16 + c];
    }

    float s1r[4], s2r[4];
#pragma unroll
    for (int reg = 0; reg < 4; ++reg) {
        float s1 = 0.f, s2 = 0.f;
#pragma unroll
        for (int ct = 0; ct < 4; ++ct) {
            s1 += acc[ct][reg] * a1c[ct];
            s2 += acc[ct][reg] * a2c[ct];
        }
        s1r[reg] = s1; s2r[reg] = s2;
    }
#pragma unroll
    for (int off = 1; off < 16; off <<= 1) {
#pragma unroll
        for (int reg = 0; reg < 4; ++reg) {
            s1r[reg] += __shfl_xor(s1r[reg], off);
            s2r[reg] += __shfl_xor(s2r[reg], off);
        }
    }
#pragma unroll
    for (int reg = 0; reg < 4; ++reg) {
        const int row = m0 + q * 4 + reg;
        if (row < N) {
#pragma unroll
            for (int ct = 0; ct < 4; ++ct)
                h_bf[(long)row * FDIM + ct * 16 + c] = __float2bfloat16(acc[ct][reg]);
            if (c == 0) { s_src[row] = s1r[reg]; s_dst[row] = s2r[reg]; }
        }
    }
}

// ---------------------------------------------------------------------------
// Kernel C (sortless scatter-gather): one block (512 thr) per 64-src bucket.
// acc[64][ACC_STRIDE] fp32 in LDS. Each 8-lane group streams one edge:
// decode, weight, 128B h row load, 8 fire-and-forget ds_add_f32 into
// acc[srclo], wsum atomic by lane 0 of the group. No barriers during
// accumulation; one barrier then divide+elu+store.
// ---------------------------------------------------------------------------
__global__ __launch_bounds__(512) void gat_scatgather_kernel(
    const u32* __restrict__ pair, const int* __restrict__ bcur,
    const float* __restrict__ s_src, const float* __restrict__ s_dst,
    const __hip_bfloat16* __restrict__ h_bf, float* __restrict__ out, int N)
{
    __shared__ float acc[64 * ACC_STRIDE];   // 16.6 KB
    __shared__ float wsum[64];
    __shared__ float ssl[64];

    const int b = (int)blockIdx.x;
    const int t = threadIdx.x;
    const int s0 = b << 6;
    const int abase = b * BUCKET_CAP;
    const int n = min(bcur[b], BUCKET_CAP);

    for (int j = t; j < 64 * ACC_STRIDE; j += 512) acc[j] = 0.f;
    if (t < 64) {
        wsum[t] = 0.f;
        ssl[t] = (s0 + t < N) ? s_src[s0 + t] : 0.f;
    }
    __syncthreads();

    const int l = t & 63;
    const int w = t >> 6;        // wave 0..7
    const int slot = l >> 3;     // edge slot 0..7
    const int oct = l & 7;       // feature octet 0..7
    const __bf16* hb = (const __bf16*)h_bf;

    // 64 edges per block-iteration (8 waves x 8 slots); waves free-run.
    for (int e = w * 8 + slot; e < n; e += 64) {
        const u32 p = pair[abase + e];
        const int sl = (int)(p >> 16);
        const int d = (int)(p & 0xFFFFu);
        const float sc = ssl[sl] + s_dst[d];
        const float lr = sc > 0.f ? sc : ALPHA * sc;
        const float wgt = __expf(-lr);
        const bf16x8 hv = *(const bf16x8*)(hb + (long)d * FDIM + 8 * oct);
        float* ap = &acc[sl * ACC_STRIDE + oct * 8];
#pragma unroll
        for (int j = 0; j < 8; ++j)
            atomicAdd(&ap[j], wgt * (float)hv[j]);
        if (oct == 0) atomicAdd(&wsum[sl], wgt);
    }
    __syncthreads();

    // epilogue: thread t -> node t>>3, octet t&7
    const int nl = t >> 3;
    const int oc = t & 7;
    const int node = s0 + nl;
    if (node < N) {
        const float inv = 1.0f / wsum[nl];
        const float* ap = &acc[nl * ACC_STRIDE + oc * 8];
        float o[8];
#pragma unroll
        for (int j = 0; j < 8; ++j) {
            const float v = ap[j] * inv;
            o[j] = v > 0.f ? v : expm1f(v);
        }
        float* op = &out[(long)node * FDIM + 8 * oc];
        *(float4*)op = make_float4(o[0], o[1], o[2], o[3]);
        *(float4*)(op + 4) = make_float4(o[4], o[5], o[6], o[7]);
    }
}

extern "C" void kernel_launch(void* const* d_in, const int* in_sizes, int n_in,
                              void* d_out, int out_size, void* d_ws, size_t ws_size,
                              hipStream_t stream) {
    const float* x = (const float*)d_in[0];
    const float* W = (const float*)d_in[1];
    const float* a = (const float*)d_in[2];
    const int* ei  = (const int*)d_in[3];

    const int N = in_sizes[0] / KDIM;       // 50000
    const int E = in_sizes[3] / 2;          // 1600000
    const int NBU = (N + 63) >> 6;          // 782 buckets of 64 srcs
    const int NBLK = (E + BIN_CHUNK - 1) / BIN_CHUNK;  // 196 bin chunks
    const int GB = (N + 63) / 64;                      // 782 gemm blocks (64 rows)
    const int* srcA = ei;
    const int* dstA = ei + E;

    // workspace layout (all regions 16B aligned; ~16 MB)
    __hip_bfloat16* h_bf = (__hip_bfloat16*)d_ws;          // N*64 bf16
    float* s_src = (float*)(h_bf + (size_t)N * FDIM);      // N
    float* s_dst = s_src + N;                              // N
    int* bcur    = (int*)(s_dst + N);                      // 1024
    u32* pair    = (u32*)(bcur + 1024);                    // NBU*CAP arena
    float* out   = (float*)d_out;

    hipMemsetAsync(bcur, 0, 1024 * sizeof(int), stream);

    gat_gemm_bin_kernel<<<dim3(NBLK + GB), dim3(256), 0, stream>>>(
        x, W, a, h_bf, s_src, s_dst, srcA, dstA, bcur, pair, N, E, NBU, NBLK);

    gat_scatgather_kernel<<<dim3(NBU), dim3(512), 0, stream>>>(
        pair, bcur, s_src, s_dst, h_bf, out, N);
}

// Round 13
// 182.113 us; speedup vs baseline: 4.4112x; 4.4112x over previous
//
#include <hip/hip_runtime.h>
#include <hip/hip_bf16.h>
#include <hip/hip_fp16.h>

// GAT layer on MI355X (gfx950).
//   x: (N=50000, K=256) fp32, W: (K=256, F=64) fp32, a: (1, 128) fp32
//   edge_index: (2, E=1600000) int (src row 0, dst row 1)
// out = elu( segsum_src(e * h[dst]) / segsum_src(e) ),
//   e = exp(-leakyrelu(s_src[src]+s_dst[dst], 0.2)), h = x@W
//
// Round 23: R22 LDS-atomic scatter was 14x worse (collision serialization)
// -- reverted. K_B profile (VALU 63-68%, HBM 17%, invariant to grid/LDS/
// occupancy) says the VALU stream itself is the cost; ~half of it is bf16
// ->f32 conversion lowering in the gather. Change: h stored as FP32 by the
// gemm (12.8MB, L3-resident), gather loads float4 pairs -- zero cvt insts.
// 2x gather bytes is free at 17% HBM. Everything else = R18 verified.

#define ALPHA 0.2f
#define KDIM 256
#define FDIM 64
#define WPAD 8             // bf16 row pad: row stride 264 elems = 528B
#define BIN_CHUNK 8192
#define BUCKET_CAP 4096    // 64-src bucket: mean ~2046 edges; >40 sigma slack
#define HCAP 2304          // 32-src half bucket: mean ~1023; ~40 sigma slack

typedef __bf16 bf16x8 __attribute__((ext_vector_type(8)));
typedef float f32x4 __attribute__((ext_vector_type(4)));
typedef unsigned int u32;
typedef unsigned short u16;

union SmemA {
    struct { int hist[1024]; int lcur[1024]; } bin;   // 8 KB
    __bf16 w[FDIM * (KDIM + WPAD)];                   // 33 KB  w[n][k]
};

// ---------------------------------------------------------------------------
// Kernel A (fused): blocks [0,NBLK) = bin; blocks [NBLK, NBLK+GB) = gemm.
// Identical to round-18 verified version except h is stored fp32.
// ---------------------------------------------------------------------------
__global__ __launch_bounds__(256) void gat_gemm_bin_kernel(
    const float* __restrict__ x, const float* __restrict__ W,
    const float* __restrict__ a, float* __restrict__ h_f,
    float* __restrict__ s_src, float* __restrict__ s_dst,
    const int* __restrict__ srcA, const int* __restrict__ dstA,
    int* __restrict__ bcur, u32* __restrict__ pair,
    int N, int E, int NBU, int NBLK)
{
    __shared__ SmemA sm;
    const int t = threadIdx.x;

    if ((int)blockIdx.x < NBLK) {
        // ---------------- bin path ----------------
        for (int j = t; j < 1024; j += 256) sm.bin.hist[j] = 0;
        __syncthreads();
        const int base = blockIdx.x * BIN_CHUNK;
        const int cnt = min(BIN_CHUNK, E - base);
        for (int i = t; i < cnt; i += 256)
            atomicAdd(&sm.bin.hist[srcA[base + i] >> 6], 1);
        __syncthreads();
        for (int j = t; j < NBU; j += 256) {
            const int v = sm.bin.hist[j];
            sm.bin.lcur[j] = v ? (j * BUCKET_CAP + atomicAdd(&bcur[j], v)) : 0;
        }
        __syncthreads();
        for (int i = t; i < cnt; i += 256) {
            const int s = srcA[base + i];
            const int d = dstA[base + i];
            const int pos = atomicAdd(&sm.bin.lcur[s >> 6], 1);
            pair[pos] = ((u32)(s & 63) << 16) | (u32)d;   // d < 65536
        }
        return;
    }

    // ---------------- gemm path ----------------
    for (int i = t; i < KDIM * FDIM; i += 256) {
        const int k = i >> 6;
        const int n = i & 63;
        sm.w[n * (KDIM + WPAD) + k] = (__bf16)W[i];
    }
    __syncthreads();

    const int gb = (int)blockIdx.x - NBLK;
    const int lane = t & 63;
    const int wv = t >> 6;              // 0..3
    const int m0 = gb * 64 + wv * 16;   // this wave: rows m0..m0+15
    const int c = lane & 15;
    const int q = lane >> 4;

    const int r0 = m0 + c;
    const float* xp0 = x + (long)(r0 < N ? r0 : N - 1) * KDIM;

    f32x4 acc[4];
#pragma unroll
    for (int ct = 0; ct < 4; ++ct) acc[ct] = (f32x4){0.f, 0.f, 0.f, 0.f};

#pragma unroll 4
    for (int kc = 0; kc < 8; ++kc) {
        const int k0 = kc * 32 + q * 8;
        const float4 xa0 = *(const float4*)(xp0 + k0);
        const float4 xb0 = *(const float4*)(xp0 + k0 + 4);
        bf16x8 af0;
        af0[0] = (__bf16)xa0.x; af0[1] = (__bf16)xa0.y;
        af0[2] = (__bf16)xa0.z; af0[3] = (__bf16)xa0.w;
        af0[4] = (__bf16)xb0.x; af0[5] = (__bf16)xb0.y;
        af0[6] = (__bf16)xb0.z; af0[7] = (__bf16)xb0.w;
#pragma unroll
        for (int ct = 0; ct < 4; ++ct) {
            const bf16x8 bf = *(const bf16x8*)(&sm.w[(ct * 16 + c) * (KDIM + WPAD) + k0]);
            acc[ct] = __builtin_amdgcn_mfma_f32_16x16x32_bf16(af0, bf, acc[ct], 0, 0, 0);
        }
    }

    float a1c[4], a2c[4];
#pragma unroll
    for (int ct = 0; ct < 4; ++ct) {
        a1c[ct] = a[ct * 16 + c];
        a2c[ct] = a[FDIM + ct * 16 + c];
    }

    float s1r[4], s2r[4];
#pragma unroll
    for (int reg = 0; reg < 4; ++reg) {
        float s1 = 0.f, s2 = 0.f;
#pragma unroll
        for (int ct = 0; ct < 4; ++ct) {
            s1 += acc[ct][reg] * a1c[ct];
            s2 += acc[ct][reg] * a2c[ct];
        }
        s1r[reg] = s1; s2r[reg] = s2;
    }
#pragma unroll
    for (int off = 1; off < 16; off <<= 1) {
#pragma unroll
        for (int reg = 0; reg < 4; ++reg) {
            s1r[reg] += __shfl_xor(s1r[reg], off);
            s2r[reg] += __shfl_xor(s2r[reg], off);
        }
    }
#pragma unroll
    for (int reg = 0; reg < 4; ++reg) {
        const int row = m0 + q * 4 + reg;
        if (row < N) {
#pragma unroll
            for (int ct = 0; ct < 4; ++ct)
                h_f[(long)row * FDIM + ct * 16 + c] = acc[ct][reg];
            if (c == 0) { s_src[row] = s1r[reg]; s_dst[row] = s2r[reg]; }
        }
    }
}

// ---------------------------------------------------------------------------
// Kernel B (fused sort+gather, half-bucket blocks): 2 blocks (256 thr) per
// 64-src bucket; block handles 32 srcs (half = blockIdx&1).
// Phase A: two passes over the bucket's (L2-resident) pair list -- count
// matching srcs, scan, scatter directly into slds with packed f16 weight.
// Phase B: segmented reduction over FP32 h (float4 pairs, zero cvt insts).
// ---------------------------------------------------------------------------
__global__ __launch_bounds__(256) void gat_sortgather_kernel(
    const u32* __restrict__ pair, const int* __restrict__ bcur,
    const float* __restrict__ s_src, const float* __restrict__ s_dst,
    const float* __restrict__ h_f, float* __restrict__ out, int N)
{
    __shared__ u32 slds[HCAP];   // 9 KB sorted (dst | f16(wgt)<<16)
    __shared__ int cur[32];
    __shared__ int nst[32];
    __shared__ int nen[32];
    __shared__ float ssl[32];

    const int b = (int)blockIdx.x >> 1;    // bucket
    const int hf = (int)blockIdx.x & 1;    // half: srcs [hf*32, hf*32+32)
    const int t = threadIdx.x;
    const int s0 = (b << 6) + (hf << 5);   // first src of this half
    const int abase = b * BUCKET_CAP;
    const int n = min(bcur[b], BUCKET_CAP);

    if (t < 32) {
        cur[t] = 0;
        ssl[t] = (s0 + t < N) ? s_src[s0 + t] : 0.f;
    }
    __syncthreads();
    // pass 1: count srcs belonging to this half
    for (int i = t; i < n; i += 256) {
        const int sl = (int)(pair[abase + i] >> 16);
        if ((sl >> 5) == hf) atomicAdd(&cur[sl & 31], 1);
    }
    __syncthreads();
    if (t < 32) {   // lanes 0..31 of wave 0: exclusive scan of 32 counts
        const int v = cur[t];
        int incl = v;
#pragma unroll
        for (int off = 1; off < 32; off <<= 1) {
            const int nv = __shfl_up(incl, off);
            if (t >= off) incl += nv;
        }
        const int excl = incl - v;
        nst[t] = excl;
        nen[t] = min(excl + v, HCAP);
        cur[t] = excl;
    }
    __syncthreads();
    // pass 2: scatter matching edges into slds with packed weight
    for (int i = t; i < n; i += 256) {
        const u32 p = pair[abase + i];
        const int sl = (int)(p >> 16);
        if ((sl >> 5) != hf) continue;
        const int d = (int)(p & 0xFFFFu);
        const int slot = atomicAdd(&cur[sl & 31], 1);
        if (slot < HCAP) {
            const float sc = ssl[sl & 31] + s_dst[d];
            const float lr = sc > 0.f ? sc : ALPHA * sc;
            const float wgt = __expf(-lr);
            const u32 wh = (u32)__half_as_ushort(__float2half(wgt));
            slds[slot] = (u32)d | (wh << 16);
        }
    }
    __syncthreads();

    // ---------------- phase B: gather from LDS edge list (fp32 h) ---------
    const int wv = t >> 6;       // 0..3
    const int lane = t & 63;
    const int q = lane >> 3;     // edge slot 0..7
    const int c = lane & 7;      // feature octet 0..7

    for (int nl = wv; nl < 32; nl += 4) {
        const int node = s0 + nl;
        if (node >= N) break;
        const int start = nst[nl];
        const int end = nen[nl];

        float acc0[8], acc1[8];
#pragma unroll
        for (int j = 0; j < 8; ++j) { acc0[j] = 0.f; acc1[j] = 0.f; }
        float wsum0 = 0.f, wsum1 = 0.f;

        int e = start + q;
        for (; e + 8 < end; e += 16) {
            const u32 p0 = slds[e];
            const u32 p1 = slds[e + 8];
            const int d0 = (int)(p0 & 0xFFFFu);
            const int d1 = (int)(p1 & 0xFFFFu);
            const float* hp0 = h_f + (long)d0 * FDIM + 8 * c;
            const float* hp1 = h_f + (long)d1 * FDIM + 8 * c;
            const float4 hva0 = *(const float4*)hp0;
            const float4 hvb0 = *(const float4*)(hp0 + 4);
            const float4 hva1 = *(const float4*)hp1;
            const float4 hvb1 = *(const float4*)(hp1 + 4);
            const float w0 = __half2float(__ushort_as_half((u16)(p0 >> 16)));
            const float w1 = __half2float(__ushort_as_half((u16)(p1 >> 16)));
            acc0[0] += w0 * hva0.x; acc0[1] += w0 * hva0.y;
            acc0[2] += w0 * hva0.z; acc0[3] += w0 * hva0.w;
            acc0[4] += w0 * hvb0.x; acc0[5] += w0 * hvb0.y;
            acc0[6] += w0 * hvb0.z; acc0[7] += w0 * hvb0.w;
            acc1[0] += w1 * hva1.x; acc1[1] += w1 * hva1.y;
            acc1[2] += w1 * hva1.z; acc1[3] += w1 * hva1.w;
            acc1[4] += w1 * hvb1.x; acc1[5] += w1 * hvb1.y;
            acc1[6] += w1 * hvb1.z; acc1[7] += w1 * hvb1.w;
            wsum0 += w0;
            wsum1 += w1;
        }
        if (e < end) {
            const u32 p0 = slds[e];
            const int d0 = (int)(p0 & 0xFFFFu);
            const float* hp0 = h_f + (long)d0 * FDIM + 8 * c;
            const float4 hva0 = *(const float4*)hp0;
            const float4 hvb0 = *(const float4*)(hp0 + 4);
            const float w0 = __half2float(__ushort_as_half((u16)(p0 >> 16)));
            acc0[0] += w0 * hva0.x; acc0[1] += w0 * hva0.y;
            acc0[2] += w0 * hva0.z; acc0[3] += w0 * hva0.w;
            acc0[4] += w0 * hvb0.x; acc0[5] += w0 * hvb0.y;
            acc0[6] += w0 * hvb0.z; acc0[7] += w0 * hvb0.w;
            wsum0 += w0;
        }

        float acc[8];
#pragma unroll
        for (int j = 0; j < 8; ++j) acc[j] = acc0[j] + acc1[j];
        float wsum = wsum0 + wsum1;

#pragma unroll
        for (int off = 8; off < 64; off <<= 1) {
#pragma unroll
            for (int j = 0; j < 8; ++j) acc[j] += __shfl_xor(acc[j], off);
            wsum += __shfl_xor(wsum, off);
        }

        if (q == 0) {
            const float inv = 1.0f / wsum;
            float o[8];
#pragma unroll
            for (int j = 0; j < 8; ++j) {
                const float v = acc[j] * inv;
                o[j] = v > 0.f ? v : expm1f(v);
            }
            float* op = &out[(long)node * FDIM + 8 * c];
            *(float4*)op = make_float4(o[0], o[1], o[2], o[3]);
            *(float4*)(op + 4) = make_float4(o[4], o[5], o[6], o[7]);
        }
    }
}

extern "C" void kernel_launch(void* const* d_in, const int* in_sizes, int n_in,
                              void* d_out, int out_size, void* d_ws, size_t ws_size,
                              hipStream_t stream) {
    const float* x = (const float*)d_in[0];
    const float* W = (const float*)d_in[1];
    const float* a = (const float*)d_in[2];
    const int* ei  = (const int*)d_in[3];

    const int N = in_sizes[0] / KDIM;       // 50000
    const int E = in_sizes[3] / 2;          // 1600000
    const int NBU = (N + 63) >> 6;          // 782 buckets of 64 srcs
    const int NBLK = (E + BIN_CHUNK - 1) / BIN_CHUNK;  // 196 bin chunks
    const int GB = (N + 63) / 64;                      // 782 gemm blocks (64 rows)
    const int* srcA = ei;
    const int* dstA = ei + E;

    // workspace layout (all regions 16B aligned; ~22 MB)
    float* h_f   = (float*)d_ws;                           // N*64 fp32
    float* s_src = h_f + (size_t)N * FDIM;                 // N
    float* s_dst = s_src + N;                              // N
    int* bcur    = (int*)(s_dst + N);                      // 1024
    u32* pair    = (u32*)(bcur + 1024);                    // NBU*CAP arena
    float* out   = (float*)d_out;

    hipMemsetAsync(bcur, 0, 1024 * sizeof(int), stream);

    gat_gemm_bin_kernel<<<dim3(NBLK + GB), dim3(256), 0, stream>>>(
        x, W, a, h_f, s_src, s_dst, srcA, dstA, bcur, pair, N, E, NBU, NBLK);

    gat_sortgather_kernel<<<dim3(NBU * 2), dim3(256), 0, stream>>>(
        pair, bcur, s_src, s_dst, h_f, out, N);
}

// Round 14
// 173.808 us; speedup vs baseline: 4.6220x; 1.0478x over previous
//
#include <hip/hip_runtime.h>
#include <hip/hip_bf16.h>
#include <hip/hip_fp16.h>

// GAT layer on MI355X (gfx950).
//   x: (N=50000, K=256) fp32, W: (K=256, F=64) fp32, a: (1, 128) fp32
//   edge_index: (2, E=1600000) int (src row 0, dst row 1)
// out = elu( segsum_src(e * h[dst]) / segsum_src(e) ),
//   e = exp(-leakyrelu(s_src[src]+s_dst[dst], 0.2)), h = x@W
//
// Round 24 (final): revert to the round-18 verified best (169.6us).
// R23's fp32-h test closed the model: the gather is fetch-bound on random
// 128B h-rows (6.4MB working set > 4MB/XCD L2; FETCH 54MB = 8 XCDs x 6.4MB),
// not VALU-bound. K_B=50us latency floor (invariant to grid/occupancy/ILP/
// prefetch; atomics 14x worse, fp32 +24% worse). K_A=52us latency floor
// (9 reconfigs invariant). Wall-sum gap ~63us = fixed harness overhead
// (dispatch-count invariant). Structure: memset(bcur) + K_A (bin 196 blk |
// gemm 782 blk, W^T in 33KB LDS) + K_B (half-bucket sort+gather, 1564 blk).

#define ALPHA 0.2f
#define KDIM 256
#define FDIM 64
#define WPAD 8             // bf16 row pad: row stride 264 elems = 528B
#define BIN_CHUNK 8192
#define BUCKET_CAP 4096    // 64-src bucket: mean ~2046 edges; >40 sigma slack
#define HCAP 2304          // 32-src half bucket: mean ~1023; ~40 sigma slack

typedef __bf16 bf16x8 __attribute__((ext_vector_type(8)));
typedef float f32x4 __attribute__((ext_vector_type(4)));
typedef unsigned int u32;
typedef unsigned short u16;

union SmemA {
    struct { int hist[1024]; int lcur[1024]; } bin;   // 8 KB
    __bf16 w[FDIM * (KDIM + WPAD)];                   // 33 KB  w[n][k]
};

// ---------------------------------------------------------------------------
// Kernel A (fused): blocks [0,NBLK) = bin; blocks [NBLK, NBLK+GB) = gemm.
// 256 threads/block.
// bin: local hist over 8192-edge chunk, one reservation atomic per
//      (block,bucket) on bcur, packed scatter (srclo<<16)|dst.
// gemm: per-block W^T in LDS (bf16, padded rows), then 1 row-tile (16 rows)
//       per wave via mfma_f32_16x16x32_bf16; 4 waves -> 64 rows/block.
// ---------------------------------------------------------------------------
__global__ __launch_bounds__(256) void gat_gemm_bin_kernel(
    const float* __restrict__ x, const float* __restrict__ W,
    const float* __restrict__ a, __hip_bfloat16* __restrict__ h_bf,
    float* __restrict__ s_src, float* __restrict__ s_dst,
    const int* __restrict__ srcA, const int* __restrict__ dstA,
    int* __restrict__ bcur, u32* __restrict__ pair,
    int N, int E, int NBU, int NBLK)
{
    __shared__ SmemA sm;
    const int t = threadIdx.x;

    if ((int)blockIdx.x < NBLK) {
        // ---------------- bin path ----------------
        for (int j = t; j < 1024; j += 256) sm.bin.hist[j] = 0;
        __syncthreads();
        const int base = blockIdx.x * BIN_CHUNK;
        const int cnt = min(BIN_CHUNK, E - base);
        for (int i = t; i < cnt; i += 256)
            atomicAdd(&sm.bin.hist[srcA[base + i] >> 6], 1);
        __syncthreads();
        for (int j = t; j < NBU; j += 256) {
            const int v = sm.bin.hist[j];
            sm.bin.lcur[j] = v ? (j * BUCKET_CAP + atomicAdd(&bcur[j], v)) : 0;
        }
        __syncthreads();
        for (int i = t; i < cnt; i += 256) {
            const int s = srcA[base + i];
            const int d = dstA[base + i];
            const int pos = atomicAdd(&sm.bin.lcur[s >> 6], 1);
            pair[pos] = ((u32)(s & 63) << 16) | (u32)d;   // d < 65536
        }
        return;
    }

    // ---------------- gemm path ----------------
    for (int i = t; i < KDIM * FDIM; i += 256) {
        const int k = i >> 6;
        const int n = i & 63;
        sm.w[n * (KDIM + WPAD) + k] = (__bf16)W[i];
    }
    __syncthreads();

    const int gb = (int)blockIdx.x - NBLK;
    const int lane = t & 63;
    const int wv = t >> 6;              // 0..3
    const int m0 = gb * 64 + wv * 16;   // this wave: rows m0..m0+15
    const int c = lane & 15;
    const int q = lane >> 4;

    const int r0 = m0 + c;
    const float* xp0 = x + (long)(r0 < N ? r0 : N - 1) * KDIM;

    f32x4 acc[4];
#pragma unroll
    for (int ct = 0; ct < 4; ++ct) acc[ct] = (f32x4){0.f, 0.f, 0.f, 0.f};

#pragma unroll 4
    for (int kc = 0; kc < 8; ++kc) {
        const int k0 = kc * 32 + q * 8;
        const float4 xa0 = *(const float4*)(xp0 + k0);
        const float4 xb0 = *(const float4*)(xp0 + k0 + 4);
        bf16x8 af0;
        af0[0] = (__bf16)xa0.x; af0[1] = (__bf16)xa0.y;
        af0[2] = (__bf16)xa0.z; af0[3] = (__bf16)xa0.w;
        af0[4] = (__bf16)xb0.x; af0[5] = (__bf16)xb0.y;
        af0[6] = (__bf16)xb0.z; af0[7] = (__bf16)xb0.w;
#pragma unroll
        for (int ct = 0; ct < 4; ++ct) {
            const bf16x8 bf = *(const bf16x8*)(&sm.w[(ct * 16 + c) * (KDIM + WPAD) + k0]);
            acc[ct] = __builtin_amdgcn_mfma_f32_16x16x32_bf16(af0, bf, acc[ct], 0, 0, 0);
        }
    }

    float a1c[4], a2c[4];
#pragma unroll
    for (int ct = 0; ct < 4; ++ct) {
        a1c[ct] = a[ct * 16 + c];
        a2c[ct] = a[FDIM + ct * 16 + c];
    }

    float s1r[4], s2r[4];
#pragma unroll
    for (int reg = 0; reg < 4; ++reg) {
        float s1 = 0.f, s2 = 0.f;
#pragma unroll
        for (int ct = 0; ct < 4; ++ct) {
            s1 += acc[ct][reg] * a1c[ct];
            s2 += acc[ct][reg] * a2c[ct];
        }
        s1r[reg] = s1; s2r[reg] = s2;
    }
#pragma unroll
    for (int off = 1; off < 16; off <<= 1) {
#pragma unroll
        for (int reg = 0; reg < 4; ++reg) {
            s1r[reg] += __shfl_xor(s1r[reg], off);
            s2r[reg] += __shfl_xor(s2r[reg], off);
        }
    }
#pragma unroll
    for (int reg = 0; reg < 4; ++reg) {
        const int row = m0 + q * 4 + reg;
        if (row < N) {
#pragma unroll
            for (int ct = 0; ct < 4; ++ct)
                h_bf[(long)row * FDIM + ct * 16 + c] = __float2bfloat16(acc[ct][reg]);
            if (c == 0) { s_src[row] = s1r[reg]; s_dst[row] = s2r[reg]; }
        }
    }
}

// ---------------------------------------------------------------------------
// Kernel B (fused sort+gather, half-bucket blocks): 2 blocks (256 thr) per
// 64-src bucket; block handles 32 srcs (half = blockIdx&1).
// Phase A: two passes over the bucket's (L2-resident) pair list -- count
// matching srcs, scan, scatter directly into slds with packed f16 weight.
// Phase B: segmented reduction over bf16 h from the LDS edge list
// (2 independent edge streams per lane).
// ---------------------------------------------------------------------------
__global__ __launch_bounds__(256) void gat_sortgather_kernel(
    const u32* __restrict__ pair, const int* __restrict__ bcur,
    const float* __restrict__ s_src, const float* __restrict__ s_dst,
    const __hip_bfloat16* __restrict__ h_bf, float* __restrict__ out, int N)
{
    __shared__ u32 slds[HCAP];   // 9 KB sorted (dst | f16(wgt)<<16)
    __shared__ int cur[32];
    __shared__ int nst[32];
    __shared__ int nen[32];
    __shared__ float ssl[32];

    const int b = (int)blockIdx.x >> 1;    // bucket
    const int hf = (int)blockIdx.x & 1;    // half: srcs [hf*32, hf*32+32)
    const int t = threadIdx.x;
    const int s0 = (b << 6) + (hf << 5);   // first src of this half
    const int abase = b * BUCKET_CAP;
    const int n = min(bcur[b], BUCKET_CAP);

    if (t < 32) {
        cur[t] = 0;
        ssl[t] = (s0 + t < N) ? s_src[s0 + t] : 0.f;
    }
    __syncthreads();
    // pass 1: count srcs belonging to this half
    for (int i = t; i < n; i += 256) {
        const int sl = (int)(pair[abase + i] >> 16);
        if ((sl >> 5) == hf) atomicAdd(&cur[sl & 31], 1);
    }
    __syncthreads();
    if (t < 32) {   // lanes 0..31 of wave 0: exclusive scan of 32 counts
        const int v = cur[t];
        int incl = v;
#pragma unroll
        for (int off = 1; off < 32; off <<= 1) {
            const int nv = __shfl_up(incl, off);
            if (t >= off) incl += nv;
        }
        const int excl = incl - v;
        nst[t] = excl;
        nen[t] = min(excl + v, HCAP);
        cur[t] = excl;
    }
    __syncthreads();
    // pass 2: scatter matching edges into slds with packed weight
    for (int i = t; i < n; i += 256) {
        const u32 p = pair[abase + i];
        const int sl = (int)(p >> 16);
        if ((sl >> 5) != hf) continue;
        const int d = (int)(p & 0xFFFFu);
        const int slot = atomicAdd(&cur[sl & 31], 1);
        if (slot < HCAP) {
            const float sc = ssl[sl & 31] + s_dst[d];
            const float lr = sc > 0.f ? sc : ALPHA * sc;
            const float wgt = __expf(-lr);
            const u32 wh = (u32)__half_as_ushort(__float2half(wgt));
            slds[slot] = (u32)d | (wh << 16);
        }
    }
    __syncthreads();

    // ---------------- phase B: gather from LDS edge list ----------------
    const int wv = t >> 6;       // 0..3
    const int lane = t & 63;
    const int q = lane >> 3;     // edge slot 0..7
    const int c = lane & 7;      // feature octet 0..7
    const __bf16* hb = (const __bf16*)h_bf;

    for (int nl = wv; nl < 32; nl += 4) {
        const int node = s0 + nl;
        if (node >= N) break;
        const int start = nst[nl];
        const int end = nen[nl];

        float acc0[8], acc1[8];
#pragma unroll
        for (int j = 0; j < 8; ++j) { acc0[j] = 0.f; acc1[j] = 0.f; }
        float wsum0 = 0.f, wsum1 = 0.f;

        int e = start + q;
        for (; e + 8 < end; e += 16) {
            const u32 p0 = slds[e];
            const u32 p1 = slds[e + 8];
            const int d0 = (int)(p0 & 0xFFFFu);
            const int d1 = (int)(p1 & 0xFFFFu);
            const bf16x8 hv0 = *(const bf16x8*)(hb + (long)d0 * FDIM + 8 * c);
            const bf16x8 hv1 = *(const bf16x8*)(hb + (long)d1 * FDIM + 8 * c);
            const float w0 = __half2float(__ushort_as_half((u16)(p0 >> 16)));
            const float w1 = __half2float(__ushort_as_half((u16)(p1 >> 16)));
#pragma unroll
            for (int j = 0; j < 8; ++j) {
                acc0[j] += w0 * (float)hv0[j];
                acc1[j] += w1 * (float)hv1[j];
            }
            wsum0 += w0;
            wsum1 += w1;
        }
        if (e < end) {
            const u32 p0 = slds[e];
            const int d0 = (int)(p0 & 0xFFFFu);
            const bf16x8 hv0 = *(const bf16x8*)(hb + (long)d0 * FDIM + 8 * c);
            const float w0 = __half2float(__ushort_as_half((u16)(p0 >> 16)));
#pragma unroll
            for (int j = 0; j < 8; ++j) acc0[j] += w0 * (float)hv0[j];
            wsum0 += w0;
        }

        float acc[8];
#pragma unroll
        for (int j = 0; j < 8; ++j) acc[j] = acc0[j] + acc1[j];
        float wsum = wsum0 + wsum1;

#pragma unroll
        for (int off = 8; off < 64; off <<= 1) {
#pragma unroll
            for (int j = 0; j < 8; ++j) acc[j] += __shfl_xor(acc[j], off);
            wsum += __shfl_xor(wsum, off);
        }

        if (q == 0) {
            const float inv = 1.0f / wsum;
            float o[8];
#pragma unroll
            for (int j = 0; j < 8; ++j) {
                const float v = acc[j] * inv;
                o[j] = v > 0.f ? v : expm1f(v);
            }
            float* op = &out[(long)node * FDIM + 8 * c];
            *(float4*)op = make_float4(o[0], o[1], o[2], o[3]);
            *(float4*)(op + 4) = make_float4(o[4], o[5], o[6], o[7]);
        }
    }
}

extern "C" void kernel_launch(void* const* d_in, const int* in_sizes, int n_in,
                              void* d_out, int out_size, void* d_ws, size_t ws_size,
                              hipStream_t stream) {
    const float* x = (const float*)d_in[0];
    const float* W = (const float*)d_in[1];
    const float* a = (const float*)d_in[2];
    const int* ei  = (const int*)d_in[3];

    const int N = in_sizes[0] / KDIM;       // 50000
    const int E = in_sizes[3] / 2;          // 1600000
    const int NBU = (N + 63) >> 6;          // 782 buckets of 64 srcs
    const int NBLK = (E + BIN_CHUNK - 1) / BIN_CHUNK;  // 196 bin chunks
    const int GB = (N + 63) / 64;                      // 782 gemm blocks (64 rows)
    const int* srcA = ei;
    const int* dstA = ei + E;

    // workspace layout (all regions 16B aligned; ~16 MB)
    __hip_bfloat16* h_bf = (__hip_bfloat16*)d_ws;          // N*64 bf16
    float* s_src = (float*)(h_bf + (size_t)N * FDIM);      // N
    float* s_dst = s_src + N;                              // N
    int* bcur    = (int*)(s_dst + N);                      // 1024
    u32* pair    = (u32*)(bcur + 1024);                    // NBU*CAP arena
    float* out   = (float*)d_out;

    hipMemsetAsync(bcur, 0, 1024 * sizeof(int), stream);

    gat_gemm_bin_kernel<<<dim3(NBLK + GB), dim3(256), 0, stream>>>(
        x, W, a, h_bf, s_src, s_dst, srcA, dstA, bcur, pair, N, E, NBU, NBLK);

    gat_sortgather_kernel<<<dim3(NBU * 2), dim3(256), 0, stream>>>(
        pair, bcur, s_src, s_dst, h_bf, out, N);
}